// Round 6
// baseline (309.936 us; speedup 1.0000x reference)
//
#include <hip/hip_runtime.h>
#include <stdint.h>

typedef unsigned short u16;
typedef __attribute__((ext_vector_type(8))) short short8;   // 8 x bf16 (4 VGPRs)
typedef __attribute__((ext_vector_type(4))) float float4v;  // MFMA 16x16 C/D

#define MFMA16(a, b, c) __builtin_amdgcn_mfma_f32_16x16x32_bf16((a), (b), (c), 0, 0, 0)

// fold softmax scale (1/8) and log2(e) into Q so p = exp2(S) directly
#define Q_SCALE 0.18033688011112042f

// XOR-swizzled address in a 64-col u16 tile: 16B chunk index ^= row&7 (0 conflicts, round 5)
__device__ __forceinline__ int swz(int row, int col) {
  return row * 64 + (col & 7) + ((((col >> 3) ^ row) & 7) << 3);
}
// 32-col u16 tile (P half-tiles): 4 chunks/row, chunk ^= (row>>1)&3 spreads the
// 16-row b128 read over both bank halves (~2-way residual = free)
__device__ __forceinline__ int swz32(int row, int col) {
  return row * 32 + (col & 7) + ((((col >> 3) ^ (row >> 1)) & 3) << 3);
}

// float -> bf16 (RNE)
__device__ __forceinline__ u16 f2b(float f) {
  union { float f; unsigned u; } x; x.f = f;
  unsigned r = x.u + 0x7fffu + ((x.u >> 16) & 1u);
  return (u16)(r >> 16);
}
// float -> bf16, round-half-up: 1 add + hi16 store (hot path)
__device__ __forceinline__ u16 f2b_fast(float f) {
  union { float f; unsigned u; } x; x.f = f;
  return (u16)((x.u + 0x8000u) >> 16);
}

// async global->LDS, 16B per lane; LDS dest = wave-uniform base + lane*16
__device__ __forceinline__ void load_lds_16(const void* g, void* l) {
  __builtin_amdgcn_global_load_lds((__attribute__((address_space(1))) void*)g,
                                   (__attribute__((address_space(3))) void*)l,
                                   16, 0, 0);
}

// ---------------- fp32 -> bf16 convert (vectorized, n % 8 == 0) ----------------
__global__ __launch_bounds__(256) void cvt_bf16(const float* __restrict__ in,
                                                u16* __restrict__ out, int n8) {
  int i = blockIdx.x * 256 + threadIdx.x;
  if (i >= n8) return;
  const float4* p = (const float4*)in + (size_t)i * 2;
  float4 a = p[0], b = p[1];
  uint4 w;
  w.x = (unsigned)f2b(a.x) | ((unsigned)f2b(a.y) << 16);
  w.y = (unsigned)f2b(a.z) | ((unsigned)f2b(a.w) << 16);
  w.z = (unsigned)f2b(b.x) | ((unsigned)f2b(b.y) << 16);
  w.w = (unsigned)f2b(b.z) | ((unsigned)f2b(b.w) << 16);
  *(uint4*)&out[(size_t)i * 8] = w;
}

// ---------------- V transpose: [bh][t][d] -> [bh][d][t], 64x64 LDS tiles ----------------
__global__ __launch_bounds__(256) void transpose_v(const u16* __restrict__ V,
                                                   u16* __restrict__ Vt) {
  __shared__ u16 tile[64][72];
  const int bh = blockIdx.y;
  const int t0 = blockIdx.x * 64;
  const int tid = threadIdx.x;
  const int r = tid >> 3, c = (tid & 7) * 8;
#pragma unroll
  for (int h = 0; h < 2; ++h) {
    uint4 v = *(const uint4*)&V[((size_t)bh * 2048 + t0 + r + h * 32) * 64 + c];
    const u16* p = (const u16*)&v;
#pragma unroll
    for (int j = 0; j < 8; ++j) tile[c + j][r + h * 32] = p[j];
  }
  __syncthreads();
#pragma unroll
  for (int h = 0; h < 2; ++h) {
    uint4 w;
    u16* p = (u16*)&w;
#pragma unroll
    for (int j = 0; j < 8; ++j) p[j] = tile[r + h * 32][c + j];
    *(uint4*)&Vt[((size_t)bh * 64 + r + h * 32) * 2048 + t0 + c] = w;
  }
}

// ---------------- GEMM: C[M,N] = A[M,K] * B[N,K]^T + bias (swizzled LDS) ----------------
template <bool QKV_OUT>
__global__ __launch_bounds__(256) void gemm_bt(const u16* __restrict__ A,
                                               const u16* __restrict__ B,
                                               const float* __restrict__ bias,
                                               float* __restrict__ Cf,
                                               u16* __restrict__ QKV,
                                               int M, int N, int K) {
  __shared__ __align__(16) u16 As[128 * 64];
  __shared__ __align__(16) u16 Bs[128 * 64];
  const int tid = threadIdx.x;
  const int lane = tid & 63;
  const int wave = tid >> 6;
  const int quad = lane >> 4;
  const int l15 = lane & 15;
  const int bm0 = blockIdx.y * 128;
  const int bn0 = blockIdx.x * 128;
  const int wm = (wave & 1) * 64;
  const int wn = (wave >> 1) * 64;

  float4v acc[4][4];
#pragma unroll
  for (int i = 0; i < 4; ++i)
#pragma unroll
    for (int j = 0; j < 4; ++j) acc[i][j] = (float4v){0.f, 0.f, 0.f, 0.f};

  // staging with swizzled SOURCE column so LDS layout is chunk^row swizzled
  const int srow = wave * 32 + (lane >> 3);
  const int scol = ((lane & 7) ^ ((lane >> 3) & 7)) * 8;

  for (int k0 = 0; k0 < K; k0 += 64) {
#pragma unroll
    for (int s = 0; s < 4; ++s) {
      const int r = s * 8;
      load_lds_16(&A[(size_t)(bm0 + srow + r) * K + k0 + scol], &As[(wave * 32 + r) * 64]);
      load_lds_16(&B[(size_t)(bn0 + srow + r) * K + k0 + scol], &Bs[(wave * 32 + r) * 64]);
    }
    __builtin_amdgcn_s_waitcnt(0);
    __syncthreads();
#pragma unroll
    for (int ks = 0; ks < 2; ++ks) {
      short8 af[4], bf[4];
#pragma unroll
      for (int t = 0; t < 4; ++t) {
        af[t] = *(const short8*)&As[swz(wm + t * 16 + l15, ks * 32 + quad * 8)];
        bf[t] = *(const short8*)&Bs[swz(wn + t * 16 + l15, ks * 32 + quad * 8)];
      }
#pragma unroll
      for (int mt = 0; mt < 4; ++mt)
#pragma unroll
        for (int nt = 0; nt < 4; ++nt)
          acc[mt][nt] = MFMA16(af[mt], bf[nt], acc[mt][nt]);
    }
    __syncthreads();
  }

#pragma unroll
  for (int mt = 0; mt < 4; ++mt) {
    const int row0 = bm0 + wm + mt * 16 + quad * 4;
#pragma unroll
    for (int nt = 0; nt < 4; ++nt) {
      const int col = bn0 + wn + nt * 16 + l15;
      const float bs = bias[col];
      if constexpr (QKV_OUT) {
        const int which = col >> 10;   // 0=q 1=k 2=v
        const int rem = col & 1023;
        const int h = rem >> 6;
        const int d = rem & 63;
        const float sc = (which == 0) ? Q_SCALE : 1.0f;  // pre-scale q for exp2 softmax
#pragma unroll
        for (int i = 0; i < 4; ++i) {
          const int t = row0 + i;
          const int b = t >> 11;
          const int tt = t & 2047;
          QKV[(size_t)which * 8388608 +
              ((size_t)(b * 16 + h) * 2048 + tt) * 64 + d] = f2b((acc[mt][nt][i] + bs) * sc);
        }
      } else {
#pragma unroll
        for (int i = 0; i < 4; ++i)
          Cf[(size_t)(row0 + i) * N + col] = acc[mt][nt][i] + bs;
      }
    }
  }
}

// ---------------- flash attention: paired q-tiles, shared kf+vf, MFMA row-sums ----------------
__global__ __launch_bounds__(256) void attn_kernel(const u16* __restrict__ QKV,
                                                   const u16* __restrict__ Vt_g,
                                                   u16* __restrict__ Y) {
  const int bx = blockIdx.x;   // 0..15
  const int bh = blockIdx.y;   // 0..63
  const int b = bh >> 4, h = bh & 15;
  const int tid = threadIdx.x;
  const int lane = tid & 63;
  const int wave = tid >> 6;
  const int quad = lane >> 4;
  const int l15 = lane & 15;
  const int qt[2] = {bx, 31 - bx};

  const u16* Qg = QKV + (size_t)bh * 2048 * 64;
  const u16* Kg = QKV + 8388608 + (size_t)bh * 2048 * 64;
  const u16* Vg = Vt_g + (size_t)bh * 64 * 2048;   // [d][t]

  __shared__ __align__(16) u16 Ks[2][64 * 64];
  __shared__ __align__(16) u16 Vt[2][64 * 64];
  __shared__ __align__(16) u16 Ps[4][2][16 * 32];  // [wave][u] P half-tile (keys of current ksv)

  // ones fragment for row-sum MFMA (bf16 1.0 = 0x3F80)
  short8 ones;
#pragma unroll
  for (int j = 0; j < 8; ++j) ones[j] = (short)0x3F80;

  // Q fragments (A layout: m = l15, k = quad*8+j); Q pre-scaled by GEMM1
  short8 qf[2][2];
#pragma unroll
  for (int u = 0; u < 2; ++u)
#pragma unroll
    for (int ks = 0; ks < 2; ++ks)
      qf[u][ks] = *(const short8*)&Qg[(size_t)(qt[u] * 64 + wave * 16 + l15) * 64 + ks * 32 + quad * 8];

  float4v o[2][4];
  float4v osum[2];   // row-sums via ones-MFMA: all lanes hold all 4 row sums
#pragma unroll
  for (int u = 0; u < 2; ++u) {
    osum[u] = (float4v){0.f, 0.f, 0.f, 0.f};
#pragma unroll
    for (int i = 0; i < 4; ++i) o[u][i] = (float4v){0.f, 0.f, 0.f, 0.f};
  }

  // staging: swizzle the global SOURCE column chunk; LDS dest stays lane-linear
  const int r8 = lane >> 3;
  const int c8 = ((lane & 7) ^ r8) * 8;
  auto stage = [&](int st_, int bufi) {
    const int sb = st_ * 64;
#pragma unroll
    for (int p = 0; p < 2; ++p) {
      const int c = wave * 2 + p;
      load_lds_16(&Kg[(size_t)(sb + c * 8 + r8) * 64 + c8], &Ks[bufi][c * 512]);
      load_lds_16(&Vg[(size_t)(c * 8 + r8) * 2048 + sb + c8], &Vt[bufi][c * 512]);
    }
  };

  const int last = qt[1];
  stage(0, 0);
  __builtin_amdgcn_s_waitcnt(0);
  __syncthreads();

  for (int st = 0; st <= last; ++st) {
    const int cur = st & 1;
    if (st < last) stage(st + 1, cur ^ 1);   // async prefetch; drained at end of iter
    const int sbase = st * 64;
    const bool both = (st <= qt[0]);         // block-uniform

    // ---- S = Q K^T for both q-tiles, sharing each kf read ----
    float4v s[2][4];
#pragma unroll
    for (int u = 0; u < 2; ++u)
#pragma unroll
      for (int nt = 0; nt < 4; ++nt) s[u][nt] = (float4v){0.f, 0.f, 0.f, 0.f};
#pragma unroll
    for (int ks = 0; ks < 2; ++ks)
#pragma unroll
      for (int nt = 0; nt < 4; ++nt) {
        const short8 kf = *(const short8*)&Ks[cur][swz(nt * 16 + l15, ks * 32 + quad * 8)];
        s[1][nt] = MFMA16(qf[1][ks], kf, s[1][nt]);
        if (both) s[0][nt] = MFMA16(qf[0][ks], kf, s[0][nt]);
      }

    // ---- mask (diag only) + p = exp2(s) ----
#pragma unroll
    for (int u = 0; u < 2; ++u) {
      if (u == 0 && !both) continue;
      if (st == qt[u]) {
        const int qrow = qt[u] * 64 + wave * 16 + quad * 4;
#pragma unroll
        for (int nt = 0; nt < 4; ++nt) {
          const int kc = sbase + nt * 16 + l15;
#pragma unroll
          for (int i = 0; i < 4; ++i)
            if (kc > qrow + i) s[u][nt][i] = -1e30f;
        }
      }
#pragma unroll
      for (int nt = 0; nt < 4; ++nt)
#pragma unroll
        for (int i = 0; i < 4; ++i)
          s[u][nt][i] = __builtin_amdgcn_exp2f(s[u][nt][i]);
    }

    // ---- PV in two key-halves; vf read once, feeds both q-tiles ----
#pragma unroll
    for (int ksv = 0; ksv < 2; ++ksv) {
      // pack P half-tiles to LDS (wave-private, in-order DS: no barriers)
#pragma unroll
      for (int u = 0; u < 2; ++u) {
        if (u == 0 && !both) continue;
#pragma unroll
        for (int nh = 0; nh < 2; ++nh)
#pragma unroll
          for (int i = 0; i < 4; ++i)
            Ps[wave][u][swz32(quad * 4 + i, nh * 16 + l15)] = f2b_fast(s[u][2 * ksv + nh][i]);
      }
      short8 pf[2];
      pf[1] = *(const short8*)&Ps[wave][1][swz32(l15, quad * 8)];
      if (both) pf[0] = *(const short8*)&Ps[wave][0][swz32(l15, quad * 8)];
      // row-sums via ones-MFMA
      osum[1] = MFMA16(pf[1], ones, osum[1]);
      if (both) osum[0] = MFMA16(pf[0], ones, osum[0]);
      // O += P V, sharing vf
#pragma unroll
      for (int dt = 0; dt < 4; ++dt) {
        const short8 vf = *(const short8*)&Vt[cur][swz(dt * 16 + l15, ksv * 32 + quad * 8)];
        o[1][dt] = MFMA16(pf[1], vf, o[1][dt]);
        if (both) o[0][dt] = MFMA16(pf[0], vf, o[0][dt]);
      }
    }

    __builtin_amdgcn_s_waitcnt(0);   // drain prefetch before buffer swap
    __syncthreads();
  }

  // epilogue: normalize by MFMA row-sums (every lane has all 4), write Y[b][t][h*64+d]
#pragma unroll
  for (int u = 0; u < 2; ++u) {
    float linv[4];
#pragma unroll
    for (int i = 0; i < 4; ++i) linv[i] = 1.0f / osum[u][i];
#pragma unroll
    for (int dt = 0; dt < 4; ++dt)
#pragma unroll
      for (int i = 0; i < 4; ++i) {
        const float v = o[u][dt][i] * linv[i];
        const int t = qt[u] * 64 + wave * 16 + quad * 4 + i;
        Y[((size_t)b * 2048 + t) * 1024 + h * 64 + dt * 16 + l15] = f2b(v);
      }
  }
}

// ---------------- launch ----------------
extern "C" void kernel_launch(void* const* d_in, const int* in_sizes, int n_in,
                              void* d_out, int out_size, void* d_ws, size_t ws_size,
                              hipStream_t stream) {
  const float* x  = (const float*)d_in[0];   // [4,2048,1024]
  const float* Wa = (const float*)d_in[1];   // [3072,1024]
  const float* ba = (const float*)d_in[2];   // [3072]
  const float* Wp = (const float*)d_in[3];   // [1024,1024]
  const float* bp = (const float*)d_in[4];   // [1024]
  float* out = (float*)d_out;                // [4,2048,1024] fp32

  u16* xb  = (u16*)d_ws;                  // 8388608  (reused as Y after GEMM1)
  u16* Wab = xb + 8388608;                // 3145728
  u16* Wpb = Wab + 3145728;               // 1048576
  u16* qkv = Wpb + 1048576;               // 3*8388608
  u16* y   = xb;                          // alias: x consumed by GEMM1 before attn writes y
  u16* vt  = (u16*)d_out;                 // 16.8MB scratch in d_out (GEMM2 overwrites later)

  cvt_bf16<<<4096, 256, 0, stream>>>(x, xb, 1048576);
  cvt_bf16<<<1536, 256, 0, stream>>>(Wa, Wab, 393216);
  cvt_bf16<<<512, 256, 0, stream>>>(Wp, Wpb, 131072);

  gemm_bt<true><<<dim3(24, 64), 256, 0, stream>>>(xb, Wab, ba, nullptr, qkv, 8192, 3072, 1024);
  transpose_v<<<dim3(32, 64), 256, 0, stream>>>(qkv + 16777216, vt);
  attn_kernel<<<dim3(16, 64), 256, 0, stream>>>(qkv, vt, y);
  gemm_bt<false><<<dim3(8, 64), 256, 0, stream>>>(y, Wpb, bp, out, nullptr, 8192, 1024, 1024);
}